// Round 15
// baseline (103.816 us; speedup 1.0000x reference)
//
#include <hip/hip_runtime.h>
#include <stdint.h>

#define NB_ 8
#define NC_ 128
#define NN_ 4096

typedef float f32x4 __attribute__((ext_vector_type(4)));
typedef _Float16 f16x8 __attribute__((ext_vector_type(8)));
typedef short s16x8 __attribute__((ext_vector_type(8)));
typedef short s16x4 __attribute__((ext_vector_type(4)));
typedef unsigned short u16x4 __attribute__((ext_vector_type(4)));

__device__ __forceinline__ uint16_t f2bf(float f) {
    union { float f; uint32_t u; } v; v.f = f;
    return (uint16_t)((v.u + 0x7FFFu + ((v.u >> 16) & 1u)) >> 16);
}
// P >= 0 (exp output): truncation safe; down-bias cancels in O/l ratio.
__device__ __forceinline__ uint16_t f2bf_trunc(float f) {
    union { float f; uint32_t u; } v; v.f = f;
    return (uint16_t)(v.u >> 16);
}
__device__ __forceinline__ float bf2f(uint16_t b) {
    union { uint32_t u; float f; } v; v.u = ((uint32_t)b) << 16;
    return v.f;
}

// ---- prep: xt = fp16 x^T [N][C] (Q loads) + fragment-ordered Kf / Vf ----
// Kf chunk (tile t, ms, cc): lane l holds x^T[t*32+ms*16+(l&15)][cc*32+(l>>4)*8+j]
//   fp16 x8, at Kf[((t*8+ms*4+cc)*64+l)*8]  (k=32 QK A/B layout, unchanged).
// Vf chunk (tile t, ms, cs): lane l holds x[cs*16+(l&15)][t*32+ms*16+(l>>4)*4+j]
//   bf16 x4, at Vf[((t*16+ms*8+cs)*64+l)*4]  (k=16 PV A layout, slot m = g*4+j
//   matching the C/D row map of the swapped-QK P output -> zero-shuffle PV).
__global__ __launch_bounds__(256) void prep_kernel(
        const float* __restrict__ pts, _Float16* __restrict__ xt,
        _Float16* __restrict__ Kf, uint16_t* __restrict__ Vf) {
    __shared__ float T[64][65];
    int bid = blockIdx.x;
    int ct = bid & 1, nt = (bid >> 1) & 63, b = bid >> 7;
    int c0 = ct * 64, n0 = nt * 64;
    int lr = threadIdx.x >> 6, lc = threadIdx.x & 63;
    const float* src = pts + ((size_t)b * NC_ + c0) * NN_ + n0;
#pragma unroll
    for (int r = 0; r < 16; ++r) {
        int cl = r * 4 + lr;
        T[cl][lc] = src[(size_t)cl * NN_ + lc];
    }
    __syncthreads();
#pragma unroll
    for (int r = 0; r < 16; ++r) {
        int nl = r * 4 + lr;
        xt[((size_t)b * NN_ + n0 + nl) * NC_ + c0 + lc] = (_Float16)T[lc][nl];
    }

    int w = threadIdx.x >> 6, l = threadIdx.x & 63, l15 = l & 15, g = l >> 4;
    _Float16* Kfb = Kf + (size_t)b * 524288;
    uint16_t* Vfb = Vf + (size_t)b * 524288;
#pragma unroll
    for (int e = 0; e < 2; ++e) {
        int q2 = w + e * 4;
        int tl = q2 >> 2, msq = (q2 >> 1) & 1, ccl = q2 & 1;
        int t = nt * 2 + tl, cc = ct * 2 + ccl;
        f16x8 kv;
#pragma unroll
        for (int j = 0; j < 8; ++j)
            kv[j] = (_Float16)T[ccl * 32 + g * 8 + j][tl * 32 + msq * 16 + l15];
        *(f16x8*)(Kfb + (((size_t)t * 8 + msq * 4 + cc) * 64 + l) * 8) = kv;
    }
#pragma unroll
    for (int e = 0; e < 2; ++e) {
        int q2 = w + e * 4;
        int tl = q2 >> 2, csl = q2 & 3;
        int t = nt * 2 + tl, cs = ct * 4 + csl;
#pragma unroll
        for (int ms = 0; ms < 2; ++ms) {
            u16x4 vv;
#pragma unroll
            for (int j = 0; j < 4; ++j)
                vv[j] = f2bf(T[csl * 16 + l15][tl * 32 + ms * 16 + g * 4 + j]);
            *(u16x4*)(Vfb + ((size_t)(t * 16 + ms * 8 + cs) * 64 + l) * 4) = vv;
        }
    }
}

// ---------------- flash: fused QK^T -> exp -> PV, fixed shift 64 ----------
// Swapped-operand QK (mfma(K,Q)) puts S^T row=m=g*4+r, col=n=l15 -> exp'd,
// packed bf16x4 IS the PV B-fragment for k=16 mfma (slot pairing) -> P never
// leaves registers: no Plds, no lgkm serialization, lsum lane-local.
// K/V staged by global_load_lds (fragment-linear, zero conflicts), dbuf,
// ONE barrier/iter. Partials self-normalized (bf16 O/l + fp32 l).
template <int MSPLIT>
__global__ __launch_bounds__(256, 2) void flash_kernel(
        const _Float16* __restrict__ xt, const _Float16* __restrict__ Kf,
        const uint16_t* __restrict__ Vf,
        uint16_t* __restrict__ Opart, float* __restrict__ lpart,
        const float* __restrict__ pts, const float* __restrict__ gamma,
        float* __restrict__ out) {
    int bid = blockIdx.x;
    int b = bid & 7;
    int rest = bid >> 3;
    int nb = rest & 15;
    int mh = rest >> 4;          // 0..MSPLIT-1
    int tid = threadIdx.x;
    int w = tid >> 6, l = tid & 63, l15 = l & 15, g = l >> 4;

    __shared__ __align__(16) uint16_t Kt[2 * 4096];   // dbuf 8KB, fragment-linear
    __shared__ __align__(16) uint16_t Vt[2 * 4096];   // dbuf 8KB, fragment-linear

    int nbase = nb * 256 + w * 64;
    const _Float16* xtb = xt + (size_t)b * NN_ * NC_;
    const char* KfB = (const char*)(Kf + (size_t)b * 524288);
    const char* VfB = (const char*)(Vf + (size_t)b * 524288);
    char* KtB = (char*)Kt;
    char* VtB = (char*)Vt;
    int so = tid * 16;           // thread's 16B slot (linear staging)

#define STAGE(TILE, BUF) do {                                                          \
        size_t gb_ = (size_t)(TILE) * 8192 + so;                                       \
        int lb_ = (BUF) * 8192 + so;                                                   \
        __builtin_amdgcn_global_load_lds(                                              \
            (const __attribute__((address_space(1))) void*)(KfB + gb_),                \
            (__attribute__((address_space(3))) void*)(KtB + lb_), 16, 0, 0);           \
        __builtin_amdgcn_global_load_lds(                                              \
            (const __attribute__((address_space(1))) void*)(KfB + gb_ + 4096),         \
            (__attribute__((address_space(3))) void*)(KtB + lb_ + 4096), 16, 0, 0);    \
        __builtin_amdgcn_global_load_lds(                                              \
            (const __attribute__((address_space(1))) void*)(VfB + gb_),                \
            (__attribute__((address_space(3))) void*)(VtB + lb_), 16, 0, 0);           \
        __builtin_amdgcn_global_load_lds(                                              \
            (const __attribute__((address_space(1))) void*)(VfB + gb_ + 4096),         \
            (__attribute__((address_space(3))) void*)(VtB + lb_ + 4096), 16, 0, 0);    \
    } while (0)

    // Q fragments: B-operand of swapped QK: col=n (l15), k=c (g*8+j)
    f16x8 q[4][4];
#pragma unroll
    for (int ns = 0; ns < 4; ++ns)
#pragma unroll
        for (int cc = 0; cc < 4; ++cc)
            q[ns][cc] = *(const f16x8*)(xtb + (size_t)(nbase + ns * 16 + l15) * NC_ + cc * 32 + g * 8);

    f32x4 acc[8][4];
#pragma unroll
    for (int cs = 0; cs < 8; ++cs)
#pragma unroll
        for (int ns = 0; ns < 4; ++ns)
            acc[cs][ns] = (f32x4){0.f, 0.f, 0.f, 0.f};
    float lsum[4] = {0.f, 0.f, 0.f, 0.f};

    const int nsteps = (MSPLIT == 4) ? 32 : 128;
    const int tile0 = mh * nsteps;

    // prologue: stage tile 0 into buffer 0
    STAGE(tile0, 0);

    for (int it = 0; it < nsteps; ++it) {
        __syncthreads();   // prefetch landed (vmcnt drained) + old-buffer reads done
        int cur = it & 1, nxt = cur ^ 1;
        if (it + 1 < nsteps) STAGE(tile0 + it + 1, nxt);

        const _Float16* Kc = (const _Float16*)(Kt + cur * 4096);
        const uint16_t* Vc = Vt + cur * 4096;

#pragma unroll
        for (int ms = 0; ms < 2; ++ms) {
            f16x8 kf[4];
#pragma unroll
            for (int cc = 0; cc < 4; ++cc)
                kf[cc] = *(const f16x8*)(Kc + (ms * 4 + cc) * 512 + l * 8);

            // swapped QK: S^T[m][n], row m = ms*16+g*4+r, col n = l15
            s16x4 pf[4];
#pragma unroll
            for (int ns = 0; ns < 4; ++ns) {
                f32x4 s = (f32x4){0.f, 0.f, 0.f, 0.f};
                __builtin_amdgcn_s_setprio(1);
#pragma unroll
                for (int cc = 0; cc < 4; ++cc)
                    s = __builtin_amdgcn_mfma_f32_16x16x32_f16(kf[cc], q[ns][cc], s, 0, 0, 0);
                __builtin_amdgcn_s_setprio(0);
                float p0 = __expf(-(s[0] + 64.f));
                float p1 = __expf(-(s[1] + 64.f));
                float p2 = __expf(-(s[2] + 64.f));
                float p3 = __expf(-(s[3] + 64.f));
                lsum[ns] += (p0 + p1) + (p2 + p3);
                s16x4 t;
                t[0] = (short)f2bf_trunc(p0);
                t[1] = (short)f2bf_trunc(p1);
                t[2] = (short)f2bf_trunc(p2);
                t[3] = (short)f2bf_trunc(p3);
                pf[ns] = t;      // = PV B-frag slots (g, j=r): P[m=ms*16+g*4+j][n]
            }

            // PV half-step k=16: acc[c][n] += V[c][m-slice] * P[m-slice][n]
            __builtin_amdgcn_s_setprio(1);
#pragma unroll
            for (int cs = 0; cs < 8; ++cs) {
                s16x4 vf = *(const s16x4*)(Vc + (ms * 8 + cs) * 256 + l * 4);
#pragma unroll
                for (int ns = 0; ns < 4; ++ns)
                    acc[cs][ns] = __builtin_amdgcn_mfma_f32_16x16x16bf16_1k(
                        vf, pf[ns], acc[cs][ns], 0, 0, 0);
            }
            __builtin_amdgcn_s_setprio(0);
        }
    }
#undef STAGE

    // lsum is lane-local per n=l15: reduce over the 4 g-groups
    float lred[4], linv[4];
#pragma unroll
    for (int ns = 0; ns < 4; ++ns) {
        float v2 = lsum[ns];
        v2 += __shfl_xor(v2, 16);
        v2 += __shfl_xor(v2, 32);
        lred[ns] = v2;
        linv[ns] = 1.0f / v2;
    }

    if (MSPLIT > 1) {
        // write self-normalized bf16 partial + fp32 l
        uint16_t* opb = Opart + (size_t)((b * 16 + nb) * MSPLIT + mh) * 32768;
#pragma unroll
        for (int cs = 0; cs < 8; ++cs)
#pragma unroll
            for (int ns = 0; ns < 4; ++ns)
#pragma unroll
                for (int r = 0; r < 4; ++r)
                    opb[(cs * 16 + g * 4 + r) * 256 + w * 64 + ns * 16 + l15] =
                        f2bf(acc[cs][ns][r] * linv[ns]);
        if (g == 0) {
            size_t lb = (size_t)((b * 16 + nb) * MSPLIT + mh) * 256;
#pragma unroll
            for (int ns = 0; ns < 4; ++ns)
                lpart[lb + w * 64 + ns * 16 + l15] = lred[ns];
        }
    } else {
        float gm = gamma[0];
        const float* ptsb = pts + (size_t)b * NC_ * NN_;
        float* outb = out + (size_t)b * NC_ * NN_;
#pragma unroll
        for (int cs = 0; cs < 8; ++cs)
#pragma unroll
            for (int ns = 0; ns < 4; ++ns)
#pragma unroll
                for (int r = 0; r < 4; ++r) {
                    size_t idx = (size_t)(cs * 16 + g * 4 + r) * NN_ + nbase + ns * 16 + l15;
                    outb[idx] = gm * acc[cs][ns][r] * linv[ns] + ptsb[idx];
                }
    }
}

// -------- epilogue: out = gamma * (sum o_i * l_i) / (sum l_i) + pts -------
template <int NS>
__global__ __launch_bounds__(256) void epi_kernel(
        const float* __restrict__ pts, const float* __restrict__ gamma,
        const uint16_t* __restrict__ Opart, const float* __restrict__ lpart,
        float* __restrict__ out) {
    size_t t = (size_t)blockIdx.x * 256 + threadIdx.x;
    size_t e = t * 4;
    int b = (int)(e >> 19);           // / (128*4096)
    int r = (int)(e & 524287);
    int c = r >> 12;
    int n = r & 4095;
    int nb = n >> 8, nl = n & 255;
    int base = (b * 16 + nb) * NS;
    f32x4 osum = (f32x4){0.f, 0.f, 0.f, 0.f};
    f32x4 lsum = (f32x4){0.f, 0.f, 0.f, 0.f};
#pragma unroll
    for (int i = 0; i < NS; ++i) {
        u16x4 o16 = *(const u16x4*)(Opart + (size_t)(base + i) * 32768 + c * 256 + nl);
        f32x4 li = *(const f32x4*)(lpart + (size_t)(base + i) * 256 + nl);
#pragma unroll
        for (int j = 0; j < 4; ++j) {
            osum[j] += bf2f(o16[j]) * li[j];
            lsum[j] += li[j];
        }
    }
    f32x4 p = *(const f32x4*)(pts + e);
    float gm = gamma[0];
    f32x4 res;
#pragma unroll
    for (int j = 0; j < 4; ++j)
        res[j] = gm * osum[j] / lsum[j] + p[j];
    *(f32x4*)(out + e) = res;
}

extern "C" void kernel_launch(void* const* d_in, const int* in_sizes, int n_in,
                              void* d_out, int out_size, void* d_ws, size_t ws_size,
                              hipStream_t stream) {
    const float* pts = (const float*)d_in[0];
    const float* gamma = (const float*)d_in[1];
    float* out = (float*)d_out;

    char* ws = (char*)d_ws;
    _Float16* xt = (_Float16*)ws;                              // 8 MB
    _Float16* Kf = (_Float16*)(ws + 8388608);                  // 8 MB
    uint16_t* Vf = (uint16_t*)(ws + 16777216);                 // 8 MB
    uint16_t* Opart = (uint16_t*)(ws + 25165824);              // 32 MB (bf16, msplit4)
    float* lpart = (float*)(ws + 25165824 + 33554432);         // 512 KB
    const size_t WS4 = 25165824ull + 33554432ull + 524288ull;  // 59.2 MB

    prep_kernel<<<1024, 256, 0, stream>>>(pts, xt, Kf, Vf);
    if (ws_size >= WS4) {
        flash_kernel<4><<<512, 256, 0, stream>>>(xt, Kf, Vf, Opart, lpart, pts, gamma, out);
        epi_kernel<4><<<4096, 256, 0, stream>>>(pts, gamma, Opart, lpart, out);
    } else {
        flash_kernel<1><<<128, 256, 0, stream>>>(xt, Kf, Vf, nullptr, nullptr, pts, gamma, out);
    }
}

// Round 16
// 92.707 us; speedup vs baseline: 1.1198x; 1.1198x over previous
//
#include <hip/hip_runtime.h>
#include <stdint.h>

#define NB_ 8
#define NC_ 128
#define NN_ 4096

typedef float f32x4 __attribute__((ext_vector_type(4)));
typedef _Float16 f16x8 __attribute__((ext_vector_type(8)));
typedef short s16x8 __attribute__((ext_vector_type(8)));
typedef unsigned short u16x4 __attribute__((ext_vector_type(4)));

__device__ __forceinline__ uint16_t f2bf(float f) {
    union { float f; uint32_t u; } v; v.f = f;
    return (uint16_t)((v.u + 0x7FFFu + ((v.u >> 16) & 1u)) >> 16);
}
// P >= 0 (exp output): truncation safe; down-bias cancels in O/l ratio.
__device__ __forceinline__ uint16_t f2bf_trunc(float f) {
    union { float f; uint32_t u; } v; v.f = f;
    return (uint16_t)(v.u >> 16);
}
__device__ __forceinline__ float bf2f(uint16_t b) {
    union { uint32_t u; float f; } v; v.u = ((uint32_t)b) << 16;
    return v.f;
}

// ---- prep: xt = fp16 x^T [N][C] (Q loads) + fragment-ordered Kf / Vf ----
// Kf chunk (tile t, ms, cc): lane l holds x^T[t*32+ms*16+(l&15)][cc*32+(l>>4)*8+j]
//   fp16 x8, at Kf[((t*8+ms*4+cc)*64+l)*8]  (k=32 QK A/B layout).
// Vf chunk (tile t, cs): lane l, slot j holds x[cs*16+(l&15)][t*32 + dualmap]
//   where dualmap(g,j) = (j<4) ? g*4+j : 16+g*4+(j-4)  -- matches the slot map
//   of the in-register P (both ms-halves) -> zero-shuffle k=32 PV.
__global__ __launch_bounds__(256) void prep_kernel(
        const float* __restrict__ pts, _Float16* __restrict__ xt,
        _Float16* __restrict__ Kf, uint16_t* __restrict__ Vf) {
    __shared__ float T[64][65];
    int bid = blockIdx.x;
    int ct = bid & 1, nt = (bid >> 1) & 63, b = bid >> 7;
    int c0 = ct * 64, n0 = nt * 64;
    int lr = threadIdx.x >> 6, lc = threadIdx.x & 63;
    const float* src = pts + ((size_t)b * NC_ + c0) * NN_ + n0;
#pragma unroll
    for (int r = 0; r < 16; ++r) {
        int cl = r * 4 + lr;
        T[cl][lc] = src[(size_t)cl * NN_ + lc];
    }
    __syncthreads();
#pragma unroll
    for (int r = 0; r < 16; ++r) {
        int nl = r * 4 + lr;
        xt[((size_t)b * NN_ + n0 + nl) * NC_ + c0 + lc] = (_Float16)T[lc][nl];
    }

    int w = threadIdx.x >> 6, l = threadIdx.x & 63, l15 = l & 15, g = l >> 4;
    _Float16* Kfb = Kf + (size_t)b * 524288;
    uint16_t* Vfb = Vf + (size_t)b * 524288;
#pragma unroll
    for (int e = 0; e < 2; ++e) {
        int q2 = w + e * 4;
        int tl = q2 >> 2, msq = (q2 >> 1) & 1, ccl = q2 & 1;
        int t = nt * 2 + tl, cc = ct * 2 + ccl;
        f16x8 kv;
#pragma unroll
        for (int j = 0; j < 8; ++j)
            kv[j] = (_Float16)T[ccl * 32 + g * 8 + j][tl * 32 + msq * 16 + l15];
        *(f16x8*)(Kfb + (((size_t)t * 8 + msq * 4 + cc) * 64 + l) * 8) = kv;
    }
#pragma unroll
    for (int e = 0; e < 2; ++e) {
        int q2 = w + e * 4;
        int tl = q2 >> 2, csl = q2 & 3;
        int t = nt * 2 + tl, cs = ct * 4 + csl;
        s16x8 vv;
#pragma unroll
        for (int j = 0; j < 8; ++j) {
            int m = (j < 4) ? (g * 4 + j) : (16 + g * 4 + (j - 4));
            vv[j] = (short)f2bf(T[csl * 16 + l15][tl * 32 + m]);
        }
        *(s16x8*)(Vfb + (((size_t)t * 8 + cs) * 64 + l) * 8) = vv;
    }
}

// ---------------- flash: fused QK^T -> exp -> PV, fixed shift 64 ----------
// Swapped-operand QK (mfma(K,Q)): S^T row m=ms*16+g*4+r, col n=l15. exp'd P
// from BOTH ms-halves packs into one bf16x8 = the k=32 PV B-fragment under
// the dualmap slot declaration (V packed identically in prep) -> P never
// leaves registers, PV uses full-rate k=32 MFMAs (32/iter, same as R14).
// K/V staged by global_load_lds (fragment-linear, zero conflicts), dbuf,
// ONE barrier/iter. Partials self-normalized (bf16 O/l + fp32 l).
template <int MSPLIT>
__global__ __launch_bounds__(256, 2) void flash_kernel(
        const _Float16* __restrict__ xt, const _Float16* __restrict__ Kf,
        const uint16_t* __restrict__ Vf,
        uint16_t* __restrict__ Opart, float* __restrict__ lpart,
        const float* __restrict__ pts, const float* __restrict__ gamma,
        float* __restrict__ out) {
    int bid = blockIdx.x;
    int b = bid & 7;
    int rest = bid >> 3;
    int nb = rest & 15;
    int mh = rest >> 4;          // 0..MSPLIT-1
    int tid = threadIdx.x;
    int w = tid >> 6, l = tid & 63, l15 = l & 15, g = l >> 4;

    __shared__ __align__(16) uint16_t Kt[2 * 4096];   // dbuf 8KB, fragment-linear
    __shared__ __align__(16) uint16_t Vt[2 * 4096];   // dbuf 8KB, fragment-linear

    int nbase = nb * 256 + w * 64;
    const _Float16* xtb = xt + (size_t)b * NN_ * NC_;
    const char* KfB = (const char*)(Kf + (size_t)b * 524288);
    const char* VfB = (const char*)(Vf + (size_t)b * 524288);
    char* KtB = (char*)Kt;
    char* VtB = (char*)Vt;
    int so = tid * 16;           // thread's 16B slot (linear staging)

#define STAGE(TILE, BUF) do {                                                          \
        size_t gb_ = (size_t)(TILE) * 8192 + so;                                       \
        int lb_ = (BUF) * 8192 + so;                                                   \
        __builtin_amdgcn_global_load_lds(                                              \
            (const __attribute__((address_space(1))) void*)(KfB + gb_),                \
            (__attribute__((address_space(3))) void*)(KtB + lb_), 16, 0, 0);           \
        __builtin_amdgcn_global_load_lds(                                              \
            (const __attribute__((address_space(1))) void*)(KfB + gb_ + 4096),         \
            (__attribute__((address_space(3))) void*)(KtB + lb_ + 4096), 16, 0, 0);    \
        __builtin_amdgcn_global_load_lds(                                              \
            (const __attribute__((address_space(1))) void*)(VfB + gb_),                \
            (__attribute__((address_space(3))) void*)(VtB + lb_), 16, 0, 0);           \
        __builtin_amdgcn_global_load_lds(                                              \
            (const __attribute__((address_space(1))) void*)(VfB + gb_ + 4096),         \
            (__attribute__((address_space(3))) void*)(VtB + lb_ + 4096), 16, 0, 0);    \
    } while (0)

    // Q fragments: B-operand of swapped QK: col=n (l15), k=c (g*8+j)
    f16x8 q[4][4];
#pragma unroll
    for (int ns = 0; ns < 4; ++ns)
#pragma unroll
        for (int cc = 0; cc < 4; ++cc)
            q[ns][cc] = *(const f16x8*)(xtb + (size_t)(nbase + ns * 16 + l15) * NC_ + cc * 32 + g * 8);

    f32x4 acc[8][4];
#pragma unroll
    for (int cs = 0; cs < 8; ++cs)
#pragma unroll
        for (int ns = 0; ns < 4; ++ns)
            acc[cs][ns] = (f32x4){0.f, 0.f, 0.f, 0.f};
    float lsum[4] = {0.f, 0.f, 0.f, 0.f};

    const int nsteps = (MSPLIT == 4) ? 32 : 128;
    const int tile0 = mh * nsteps;

    // prologue: stage tile 0 into buffer 0
    STAGE(tile0, 0);

    for (int it = 0; it < nsteps; ++it) {
        __syncthreads();   // prefetch landed (vmcnt drained) + old-buffer reads done
        int cur = it & 1, nxt = cur ^ 1;
        if (it + 1 < nsteps) STAGE(tile0 + it + 1, nxt);

        const _Float16* Kc = (const _Float16*)(Kt + cur * 4096);
        const uint16_t* Vc = Vt + cur * 4096;

        s16x8 pf[4];
#pragma unroll
        for (int ms = 0; ms < 2; ++ms) {
            f16x8 kf[4];
#pragma unroll
            for (int cc = 0; cc < 4; ++cc)
                kf[cc] = *(const f16x8*)(Kc + (ms * 4 + cc) * 512 + l * 8);

            // swapped QK: S^T[m][n], row m = ms*16+g*4+r, col n = l15
#pragma unroll
            for (int ns = 0; ns < 4; ++ns) {
                f32x4 s = (f32x4){0.f, 0.f, 0.f, 0.f};
                __builtin_amdgcn_s_setprio(1);
#pragma unroll
                for (int cc = 0; cc < 4; ++cc)
                    s = __builtin_amdgcn_mfma_f32_16x16x32_f16(kf[cc], q[ns][cc], s, 0, 0, 0);
                __builtin_amdgcn_s_setprio(0);
                float p0 = __expf(-(s[0] + 64.f));
                float p1 = __expf(-(s[1] + 64.f));
                float p2 = __expf(-(s[2] + 64.f));
                float p3 = __expf(-(s[3] + 64.f));
                lsum[ns] += (p0 + p1) + (p2 + p3);
                // slot j = ms*4 + r declares m = ms*16 + g*4 + r  (dualmap)
                pf[ns][ms * 4 + 0] = (short)f2bf_trunc(p0);
                pf[ns][ms * 4 + 1] = (short)f2bf_trunc(p1);
                pf[ns][ms * 4 + 2] = (short)f2bf_trunc(p2);
                pf[ns][ms * 4 + 3] = (short)f2bf_trunc(p3);
            }
        }

        // PV k=32: acc[c][n] += V[c][m] * P[m][n], full 32-m tile at once
        __builtin_amdgcn_s_setprio(1);
#pragma unroll
        for (int cs = 0; cs < 8; ++cs) {
            s16x8 vf = *(const s16x8*)(Vc + cs * 512 + l * 8);
#pragma unroll
            for (int ns = 0; ns < 4; ++ns)
                acc[cs][ns] = __builtin_amdgcn_mfma_f32_16x16x32_bf16(vf, pf[ns], acc[cs][ns], 0, 0, 0);
        }
        __builtin_amdgcn_s_setprio(0);
    }
#undef STAGE

    // lsum is lane-local per n=l15: reduce over the 4 g-groups
    float lred[4], linv[4];
#pragma unroll
    for (int ns = 0; ns < 4; ++ns) {
        float v2 = lsum[ns];
        v2 += __shfl_xor(v2, 16);
        v2 += __shfl_xor(v2, 32);
        lred[ns] = v2;
        linv[ns] = 1.0f / v2;
    }

    if (MSPLIT > 1) {
        // write self-normalized bf16 partial + fp32 l
        uint16_t* opb = Opart + (size_t)((b * 16 + nb) * MSPLIT + mh) * 32768;
#pragma unroll
        for (int cs = 0; cs < 8; ++cs)
#pragma unroll
            for (int ns = 0; ns < 4; ++ns)
#pragma unroll
                for (int r = 0; r < 4; ++r)
                    opb[(cs * 16 + g * 4 + r) * 256 + w * 64 + ns * 16 + l15] =
                        f2bf(acc[cs][ns][r] * linv[ns]);
        if (g == 0) {
            size_t lb = (size_t)((b * 16 + nb) * MSPLIT + mh) * 256;
#pragma unroll
            for (int ns = 0; ns < 4; ++ns)
                lpart[lb + w * 64 + ns * 16 + l15] = lred[ns];
        }
    } else {
        float gm = gamma[0];
        const float* ptsb = pts + (size_t)b * NC_ * NN_;
        float* outb = out + (size_t)b * NC_ * NN_;
#pragma unroll
        for (int cs = 0; cs < 8; ++cs)
#pragma unroll
            for (int ns = 0; ns < 4; ++ns)
#pragma unroll
                for (int r = 0; r < 4; ++r) {
                    size_t idx = (size_t)(cs * 16 + g * 4 + r) * NN_ + nbase + ns * 16 + l15;
                    outb[idx] = gm * acc[cs][ns][r] * linv[ns] + ptsb[idx];
                }
    }
}

// -------- epilogue: out = gamma * (sum o_i * l_i) / (sum l_i) + pts -------
template <int NS>
__global__ __launch_bounds__(256) void epi_kernel(
        const float* __restrict__ pts, const float* __restrict__ gamma,
        const uint16_t* __restrict__ Opart, const float* __restrict__ lpart,
        float* __restrict__ out) {
    size_t t = (size_t)blockIdx.x * 256 + threadIdx.x;
    size_t e = t * 4;
    int b = (int)(e >> 19);           // / (128*4096)
    int r = (int)(e & 524287);
    int c = r >> 12;
    int n = r & 4095;
    int nb = n >> 8, nl = n & 255;
    int base = (b * 16 + nb) * NS;
    f32x4 osum = (f32x4){0.f, 0.f, 0.f, 0.f};
    f32x4 lsum = (f32x4){0.f, 0.f, 0.f, 0.f};
#pragma unroll
    for (int i = 0; i < NS; ++i) {
        u16x4 o16 = *(const u16x4*)(Opart + (size_t)(base + i) * 32768 + c * 256 + nl);
        f32x4 li = *(const f32x4*)(lpart + (size_t)(base + i) * 256 + nl);
#pragma unroll
        for (int j = 0; j < 4; ++j) {
            osum[j] += bf2f(o16[j]) * li[j];
            lsum[j] += li[j];
        }
    }
    f32x4 p = *(const f32x4*)(pts + e);
    float gm = gamma[0];
    f32x4 res;
#pragma unroll
    for (int j = 0; j < 4; ++j)
        res[j] = gm * osum[j] / lsum[j] + p[j];
    *(f32x4*)(out + e) = res;
}

extern "C" void kernel_launch(void* const* d_in, const int* in_sizes, int n_in,
                              void* d_out, int out_size, void* d_ws, size_t ws_size,
                              hipStream_t stream) {
    const float* pts = (const float*)d_in[0];
    const float* gamma = (const float*)d_in[1];
    float* out = (float*)d_out;

    char* ws = (char*)d_ws;
    _Float16* xt = (_Float16*)ws;                              // 8 MB
    _Float16* Kf = (_Float16*)(ws + 8388608);                  // 8 MB
    uint16_t* Vf = (uint16_t*)(ws + 16777216);                 // 8 MB
    uint16_t* Opart = (uint16_t*)(ws + 25165824);              // 32 MB (bf16, msplit4)
    float* lpart = (float*)(ws + 25165824 + 33554432);         // 512 KB
    const size_t WS4 = 25165824ull + 33554432ull + 524288ull;  // 59.2 MB

    prep_kernel<<<1024, 256, 0, stream>>>(pts, xt, Kf, Vf);
    if (ws_size >= WS4) {
        flash_kernel<4><<<512, 256, 0, stream>>>(xt, Kf, Vf, Opart, lpart, pts, gamma, out);
        epi_kernel<4><<<4096, 256, 0, stream>>>(pts, gamma, Opart, lpart, out);
    } else {
        flash_kernel<1><<<128, 256, 0, stream>>>(xt, Kf, Vf, nullptr, nullptr, pts, gamma, out);
    }
}